// Round 6
// baseline (362.521 us; speedup 1.0000x reference)
//
#include <hip/hip_runtime.h>
#include <hip/hip_cooperative_groups.h>
namespace cg = cooperative_groups;

#define N_NODES 50000
#define N_EDGES 1600000
#define NB 782            // buckets of 64 dst nodes == grid blocks
#define NBK 782           // edge chunks (== NB, one per block)
#define CH 2048           // edges per chunk: 782*2048 >= 1.6M
#define ZROW 50000        // dummy src row (all zeros) for padding
#define NTILES 3125       // 50000 / 16 exact

typedef unsigned short ushort_t;
typedef _Float16 v8h __attribute__((ext_vector_type(8)));
typedef float f32x4_t __attribute__((ext_vector_type(4)));

__device__ __forceinline__ int rlanei(int v, int l) {
  return __builtin_amdgcn_readlane(v, l);
}

// ================= fused CSR build (cooperative, 782 blocks) =================
// A: per-chunk LDS histogram -> cnt[blk*NB+b]
// B: bucket sums -> bsum[b]; local counting sort of chunk -> bins (coalesced)
//    + per-(chunk,bucket) offsets loc[blk*(NB+1)+b]
// D: bucket b gathers its segments, builds padded per-node lists -> srcp,
//    rowiv, dinv, xp (fp16 premultiplied rows)
__global__ __launch_bounds__(256, 4) void k_build(
    const int* __restrict__ ei, int* __restrict__ cnt, int* __restrict__ bsum,
    ushort_t* __restrict__ loc, int* __restrict__ bins,
    const float* __restrict__ x, ushort_t* __restrict__ srcp,
    int2* __restrict__ rowiv, float* __restrict__ dinv,
    _Float16* __restrict__ xp) {
  __shared__ int h[NB];
  __shared__ int hB[NB];
  __shared__ int ebuf[3072];        // chunk sort staging / bucket edge list
  __shared__ ushort_t buf[3584];    // padded srcp staging
  __shared__ int scanTmp[256];
  __shared__ int dg[64], lo[64], cur64[64];
  __shared__ float sdin[64];
  __shared__ int misc[4];
  cg::grid_group grid = cg::this_grid();
  int tid = threadIdx.x, blk = blockIdx.x;
  int e0 = blk * CH;
  int e1 = min(e0 + CH, N_EDGES);
  int clen = e1 - e0;

  // ---- phase A: histogram of this chunk ----
  for (int i = tid; i < NB; i += 256) h[i] = 0;
  __syncthreads();
  for (int i = e0 + tid; i < e1; i += 256)
    atomicAdd(&h[ei[N_EDGES + i] >> 6], 1);
  __syncthreads();
  for (int b = tid; b < NB; b += 256) cnt[blk * NB + b] = h[b];
  grid.sync();

  // ---- phase B job1: bucket sums (bucket j == blk) ----
  {
    int part = 0;
    for (int i = tid; i < NBK; i += 256) part += cnt[i * NB + blk];
    scanTmp[tid] = part;
    __syncthreads();
    for (int off = 128; off > 0; off >>= 1) {
      if (tid < off) scanTmp[tid] += scanTmp[tid + off];
      __syncthreads();
    }
    if (tid == 0) bsum[blk] = scanTmp[0];
    __syncthreads();
  }

  // ---- phase B job2: local counting sort of this chunk ----
  {
    int vals[4]; int ts = 0;
    int base4 = tid * 4;
    #pragma unroll
    for (int r = 0; r < 4; ++r) {
      int idx = base4 + r;
      int v = (idx < NB) ? h[idx] : 0;
      vals[r] = v; ts += v;
    }
    scanTmp[tid] = ts;
    __syncthreads();
    for (int off = 1; off < 256; off <<= 1) {
      int u = (tid >= off) ? scanTmp[tid - off] : 0;
      __syncthreads();
      scanTmp[tid] += u;
      __syncthreads();
    }
    int ex = scanTmp[tid] - ts;   // exclusive prefix over threads
    #pragma unroll
    for (int r = 0; r < 4; ++r) {
      int idx = base4 + r;
      if (idx < NB) {
        hB[idx] = ex;                              // cursor
        loc[blk * (NB + 1) + idx] = (ushort_t)ex;  // segment start
      }
      ex += vals[r];
    }
    if (tid == 0) loc[blk * (NB + 1) + NB] = (ushort_t)clen;
    __syncthreads();
    for (int i = e0 + tid; i < e1; i += 256) {
      int s = ei[i];
      int d = ei[N_EDGES + i];
      int p = atomicAdd(&hB[d >> 6], 1);
      ebuf[p] = s | ((d & 63) << 16);   // src < 65536 fits 16 bits
    }
    __syncthreads();
    for (int i = tid; i < clen; i += 256) bins[e0 + i] = ebuf[i];  // coalesced
  }
  grid.sync();

  // ---- phase D: per-bucket build (bucket b == blk) ----
  int b = blk;
  {
    int part = 0;
    for (int j = tid; j < b; j += 256) part += bsum[j];
    scanTmp[tid] = part;
    __syncthreads();
    for (int off = 128; off > 0; off >>= 1) {
      if (tid < off) scanTmp[tid] += scanTmp[tid + off];
      __syncthreads();
    }
    if (tid == 0) { misc[1] = scanTmp[0]; misc[0] = 0; }
    __syncthreads();
  }
  int boffb = misc[1];
  // gather this bucket's segments from every chunk into LDS
  for (int j = tid; j < NBK; j += 256) {
    int l0 = loc[j * (NB + 1) + b];
    int l1 = loc[j * (NB + 1) + b + 1];
    int len = l1 - l0;
    if (len > 0) {
      int pos = atomicAdd(&misc[0], len);
      for (int k2 = 0; k2 < len; ++k2)
        ebuf[pos + k2] = bins[j * CH + l0 + k2];
    }
  }
  __syncthreads();
  int nEd = misc[0];
  if (tid < 64) dg[tid] = 0;
  __syncthreads();
  for (int i = tid; i < nEd; i += 256) atomicAdd(&dg[ebuf[i] >> 16], 1);
  __syncthreads();
  int pdv = 0;
  if (tid < 64) { pdv = (dg[tid] + 7) & ~7; lo[tid] = pdv; }
  __syncthreads();
  for (int off = 1; off < 64; off <<= 1) {
    int u = 0;
    if (tid < 64 && tid >= off) u = lo[tid - off];
    __syncthreads();
    if (tid < 64) lo[tid] += u;
    __syncthreads();
  }
  int ex2 = 0;
  if (tid < 64) {
    ex2 = lo[tid] - pdv;
    cur64[tid] = ex2;
    if (tid == 63) misc[2] = lo[63];
  }
  __syncthreads();
  int T = misc[2];
  int sbase = boffb + b * 512;      // 512 > 64*7 max padding slack
  for (int i = tid; i < T; i += 256) buf[i] = (ushort_t)ZROW;
  __syncthreads();
  for (int i = tid; i < nEd; i += 256) {
    int v = ebuf[i];
    int p = atomicAdd(&cur64[v >> 16], 1);
    buf[p] = (ushort_t)(v & 0xFFFF);
  }
  __syncthreads();
  for (int i = tid; i < T; i += 256) srcp[sbase + i] = buf[i];
  if (tid < 64) {
    int v = b * 64 + tid;
    if (v < N_NODES) {
      rowiv[v] = make_int2(sbase + ex2, pdv);
      float dv = rsqrtf((float)dg[tid] + 2.0f);
      dinv[v] = dv;
      sdin[tid] = dv;
    } else {
      sdin[tid] = 0.f;
    }
  }
  __syncthreads();
  int nb64 = b * 4096;
  for (int idx = tid; idx < 4096; idx += 256) {
    int v = b * 64 + (idx >> 6);
    if (v < N_NODES) xp[nb64 + idx] = (_Float16)(sdin[idx >> 6] * x[nb64 + idx]);
  }
  if (b == 0 && tid < 64) xp[ZROW * 64 + tid] = (_Float16)0.f;
}

// ========== weight prep: compose + pack B-fragments in one kernel ==========
// Bzh[t]: frag=t>>9, lane=(t>>3)&63, j=t&7; ntile=frag>>1, ks=frag&1;
// n=ntile*16+(lane&15), k=ks*32+((lane>>4)<<3)+j.
// value = (W? @ Wl?[:64])[k][n'] computed as a direct 64-dot (no M buffer).
__global__ __launch_bounds__(256) void k_wprep(
    const float* __restrict__ Wz, const float* __restrict__ bz,
    const float* __restrict__ Wlz, const float* __restrict__ blz,
    const float* __restrict__ Wh, const float* __restrict__ bh,
    const float* __restrict__ Wlh, const float* __restrict__ blh,
    const float* __restrict__ Wout,
    float2* __restrict__ B2, _Float16* __restrict__ Bzh,
    _Float16* __restrict__ Bwo) {
  int t = blockIdx.x * 256 + threadIdx.x;   // 8192 threads
  {
    int lane = (t >> 3) & 63, j = t & 7;
    int ntile = t >> 10, ks = (t >> 9) & 1;
    int n = ntile * 16 + (lane & 15);
    int k = ks * 32 + ((lane >> 4) << 3) + j;
    float acc = 0.f;
    if (n < 64) {
      for (int q = 0; q < 64; ++q) acc = fmaf(Wz[k * 64 + q], Wlz[q * 64 + n], acc);
    } else {
      int n2 = n - 64;
      for (int q = 0; q < 64; ++q) acc = fmaf(Wh[k * 64 + q], Wlh[q * 64 + n2], acc);
    }
    Bzh[t] = (_Float16)acc;
  }
  if (t < 3072) {
    int lane = (t >> 3) & 63, j = t & 7;
    int ntile = t >> 10, ks = (t >> 9) & 1;
    int n = ntile * 16 + (lane & 15);
    int k = ks * 32 + ((lane >> 4) << 3) + j;
    Bwo[t] = (_Float16)((n < 45) ? Wout[k * 45 + n] : 0.f);
  }
  if (t < 64) {
    float vz = blz[t], vh = blh[t];
    for (int q = 0; q < 64; ++q) {
      vz = fmaf(bz[q], Wlz[q * 64 + t], vz);
      vh = fmaf(bh[q], Wlh[q * 64 + t], vh);
    }
    B2[t] = make_float2(vz, vh);
  }
}

// ---------------- gather: one wave per node, register accumulate ----------
__global__ __launch_bounds__(256) void k_agg(
    const ushort_t* __restrict__ srcp, const int2* __restrict__ rowiv,
    const float* __restrict__ dinv, const _Float16* __restrict__ xp,
    _Float16* __restrict__ sxg) {
  int tid = threadIdx.x;
  int lane = tid & 63;
  int w = blockIdx.x * 4 + (tid >> 6);
  int nw = gridDim.x * 4;
  for (int v = w; v < N_NODES; v += nw) {
    int vu = __builtin_amdgcn_readfirstlane(v);
    int2 ri = rowiv[vu];
    int beg = ri.x, pd = ri.y;
    float a0 = 0.f, a1 = 0.f;
    for (int e = beg; e < beg + pd; e += 64) {
      int rem = beg + pd - e;
      int m = rem < 64 ? rem : 64;   // multiple of 8
      int sv = ZROW;
      if (lane < m) sv = srcp[e + lane];
      for (int j = 0; j < m; j += 8) {
        int s0 = rlanei(sv, j),     s1 = rlanei(sv, j + 1);
        int s2 = rlanei(sv, j + 2), s3 = rlanei(sv, j + 3);
        int s4 = rlanei(sv, j + 4), s5 = rlanei(sv, j + 5);
        int s6 = rlanei(sv, j + 6), s7 = rlanei(sv, j + 7);
        a0 += (float)xp[s0 * 64 + lane];
        a1 += (float)xp[s1 * 64 + lane];
        a0 += (float)xp[s2 * 64 + lane];
        a1 += (float)xp[s3 * 64 + lane];
        a0 += (float)xp[s4 * 64 + lane];
        a1 += (float)xp[s5 * 64 + lane];
        a0 += (float)xp[s6 * 64 + lane];
        a1 += (float)xp[s7 * 64 + lane];
      }
    }
    float dv = dinv[vu];
    float self = (float)xp[vu * 64 + lane];
    sxg[vu * 64 + lane] = (_Float16)(dv * (a0 + a1) + 2.f * dv * self);
  }
}

// ---------------- MFMA cell + readout (one wave per 16-node tile) ---------
__global__ __launch_bounds__(256) void k_cell(
    const _Float16* __restrict__ sxg, const _Float16* __restrict__ Bzh,
    const _Float16* __restrict__ Bwo, const float2* __restrict__ B2,
    const float* __restrict__ bout, float* __restrict__ out) {
  __shared__ __align__(16) _Float16 tbuf[4][16][72];
  int tid = threadIdx.x;
  int lane = tid & 63, wv = tid >> 6;
  int l15 = lane & 15, quad = lane >> 4;
  int tile = blockIdx.x * 4 + wv;
  if (tile >= NTILES) return;    // no barriers in this kernel -> safe

  v8h bzf[8][2], bwf[3][2];
  #pragma unroll
  for (int t = 0; t < 8; ++t)
    #pragma unroll
    for (int ks = 0; ks < 2; ++ks)
      bzf[t][ks] = *(const v8h*)(Bzh + (((t * 2 + ks) * 64 + lane) << 3));
  #pragma unroll
  for (int t = 0; t < 3; ++t)
    #pragma unroll
    for (int ks = 0; ks < 2; ++ks)
      bwf[t][ks] = *(const v8h*)(Bwo + (((t * 2 + ks) * 64 + lane) << 3));
  float zb[4], hb[4], ob[3];
  #pragma unroll
  for (int t = 0; t < 4; ++t) {
    float2 bb = B2[t * 16 + l15];
    zb[t] = bb.x; hb[t] = bb.y;
  }
  #pragma unroll
  for (int t = 0; t < 3; ++t) {
    int c = t * 16 + l15;
    ob[t] = (c < 45) ? bout[c] : 0.f;
  }

  const _Float16* ar = sxg + (tile * 16 + l15) * 64 + quad * 8;
  v8h a0 = *(const v8h*)ar;
  v8h a1 = *(const v8h*)(ar + 32);

  f32x4_t accz[8];
  #pragma unroll
  for (int t = 0; t < 8; ++t) {
    f32x4_t c4 = {0.f, 0.f, 0.f, 0.f};
    c4 = __builtin_amdgcn_mfma_f32_16x16x32_f16(a0, bzf[t][0], c4, 0, 0, 0);
    c4 = __builtin_amdgcn_mfma_f32_16x16x32_f16(a1, bzf[t][1], c4, 0, 0, 0);
    accz[t] = c4;
  }

  #pragma unroll
  for (int t = 0; t < 4; ++t) {
    #pragma unroll
    for (int r = 0; r < 4; ++r) {
      float zv = accz[t][r] + zb[t];
      float hv = accz[t + 4][r] + hb[t];
      float Z = 1.f / (1.f + __expf(-zv));
      float tt = fminf(15.f, fmaxf(-15.f, hv));
      float e2 = __expf(-2.f * tt);
      float Th = (1.f - e2) / (1.f + e2);
      tbuf[wv][quad * 4 + r][t * 16 + l15] = (_Float16)fmaxf((1.f - Z) * Th, 0.f);
    }
  }
  __asm__ volatile("s_waitcnt lgkmcnt(0)" ::: "memory");

  v8h p0 = *(const v8h*)&tbuf[wv][l15][quad * 8];
  v8h p1 = *(const v8h*)&tbuf[wv][l15][32 + quad * 8];

  #pragma unroll
  for (int t = 0; t < 3; ++t) {
    f32x4_t o4 = {0.f, 0.f, 0.f, 0.f};
    o4 = __builtin_amdgcn_mfma_f32_16x16x32_f16(p0, bwf[t][0], o4, 0, 0, 0);
    o4 = __builtin_amdgcn_mfma_f32_16x16x32_f16(p1, bwf[t][1], o4, 0, 0, 0);
    int c = t * 16 + l15;
    if (c < 45) {
      #pragma unroll
      for (int r = 0; r < 4; ++r)
        out[(tile * 16 + quad * 4 + r) * 45 + c] = o4[r] + ob[t];
    }
  }
}

// ---------------- launch ----------------
extern "C" void kernel_launch(void* const* d_in, const int* in_sizes, int n_in,
                              void* d_out, int out_size, void* d_ws, size_t ws_size,
                              hipStream_t stream) {
  const float* x    = (const float*)d_in[0];
  const int*   ei   = (const int*)d_in[1];
  const float* Wz   = (const float*)d_in[2];
  const float* bz   = (const float*)d_in[3];
  const float* Wlz  = (const float*)d_in[4];
  const float* blz  = (const float*)d_in[5];
  // d_in[6..9] (W_r branch) dead: H=0 => H*R=0.
  const float* Wh   = (const float*)d_in[10];
  const float* bh   = (const float*)d_in[11];
  const float* Wlh  = (const float*)d_in[12];
  const float* blh  = (const float*)d_in[13];
  const float* Wout = (const float*)d_in[14];
  const float* bout = (const float*)d_in[15];
  float* out = (float*)d_out;

  char* w = (char*)d_ws;
  int*      cnt   = (int*)(w + 0);            // 782*782*4 = 2,446,096
  int*      bins  = (int*)(w + 2446096);      // 6,400,000 -> ends 8,846,096
  ushort_t* loc   = (ushort_t*)(w + 8846096); // 782*783*2 = 1,224,612
  int*      bsum  = (int*)(w + 10070720);     // 3,128
  _Float16* sxg   = (_Float16*)(w + 0);       // 6.4 MB, aliases dead cnt+bins
  ushort_t* srcp  = (ushort_t*)(w + 10073856);// 2,000,384*2 = 4,000,768
  int2*     rowiv = (int2*)(w + 14074624);    // 400,000
  float*    dinv  = (float*)(w + 14474624);   // 200,000
  float2*   B2    = (float2*)(w + 14674624);  // 512
  _Float16* Bzh   = (_Float16*)(w + 14675136);// 16,384
  _Float16* Bwo   = (_Float16*)(w + 14691520);// 6,144
  _Float16* xp    = (_Float16*)(w + 14697664);// 6,400,128 -> ends ~21.1 MB

  k_wprep<<<32, 256, 0, stream>>>(Wz, bz, Wlz, blz, Wh, bh, Wlh, blh, Wout,
                                  B2, Bzh, Bwo);
  {
    void* args[] = {(void*)&ei, (void*)&cnt, (void*)&bsum, (void*)&loc,
                    (void*)&bins, (void*)&x, (void*)&srcp, (void*)&rowiv,
                    (void*)&dinv, (void*)&xp};
    hipLaunchCooperativeKernel((const void*)k_build, dim3(NBK), dim3(256),
                               args, 0, stream);
  }
  k_agg <<<2048, 256, 0, stream>>>(srcp, rowiv, dinv, xp, sxg);
  k_cell<<<NB, 256, 0, stream>>>(sxg, Bzh, Bwo, B2, bout, out);
}

// Round 7
// 179.044 us; speedup vs baseline: 2.0248x; 2.0248x over previous
//
#include <hip/hip_runtime.h>

#define N_NODES 50000
#define N_EDGES 1600000
#define NB 782            // buckets of 64 dst nodes: ceil(50000/64)
#define NBB 256           // binning blocks
#define CHUNK 6250        // N_EDGES / NBB (exact, even)
#define ZROW 50000        // dummy src row (all zeros) for padding
#define NTILES 3125       // 50000 / 16 exact

typedef unsigned short ushort_t;
typedef _Float16 v8h __attribute__((ext_vector_type(8)));
typedef _Float16 v4h __attribute__((ext_vector_type(4)));
typedef float f32x4_t __attribute__((ext_vector_type(4)));

__device__ __forceinline__ int rlanei(int v, int l) {
  return __builtin_amdgcn_readlane(v, l);
}

// ---------------- pass 1: per-(bucket,block) histogram ----------------
__global__ void k_hist(const int* __restrict__ ei, int* __restrict__ cnt) {
  __shared__ int h[NB];
  int tid = threadIdx.x, blk = blockIdx.x;
  for (int i = tid; i < NB; i += 256) h[i] = 0;
  __syncthreads();
  const int2* d2 = (const int2*)(ei + N_EDGES + blk * CHUNK);
  for (int i = tid; i < CHUNK / 2; i += 256) {
    int2 d = d2[i];
    atomicAdd(&h[d.x >> 6], 1);
    atomicAdd(&h[d.y >> 6], 1);
  }
  __syncthreads();
  for (int b = tid; b < NB; b += 256) cnt[b * NBB + blk] = h[b];
}

// ---------------- scans ----------------
__global__ void k_scanA(const int* __restrict__ cnt, int* __restrict__ bsum) {
  __shared__ int sm[256];
  int t = threadIdx.x;
  sm[t] = cnt[blockIdx.x * 256 + t];
  __syncthreads();
  for (int off = 128; off > 0; off >>= 1) {
    if (t < off) sm[t] += sm[t + off];
    __syncthreads();
  }
  if (t == 0) bsum[blockIdx.x] = sm[0];
}

__global__ void k_scanB(const int* __restrict__ bsum, int* __restrict__ boff) {
  __shared__ int sm[1024];
  int t = threadIdx.x;
  int v = (t < NB) ? bsum[t] : 0;
  sm[t] = v;
  __syncthreads();
  for (int off = 1; off < 1024; off <<= 1) {
    int u = (t >= off) ? sm[t - off] : 0;
    __syncthreads();
    sm[t] += u;
    __syncthreads();
  }
  if (t < NB) boff[t] = sm[t] - v;  // exclusive bucket start
  if (t == 0) boff[NB] = N_EDGES;
}

__global__ void k_scanC(int* __restrict__ cnt, const int* __restrict__ boff) {
  __shared__ int sm[256];
  int t = threadIdx.x, j = blockIdx.x;
  int v = cnt[j * 256 + t];
  sm[t] = v;
  __syncthreads();
  for (int off = 1; off < 256; off <<= 1) {
    int u = (t >= off) ? sm[t - off] : 0;
    __syncthreads();
    sm[t] += u;
    __syncthreads();
  }
  cnt[j * 256 + t] = boff[j] + sm[t] - v;
}

// ---------------- pass 2: binned scatter (block-private regions) ----------
__global__ void k_bin(const int* __restrict__ ei, const int* __restrict__ offs,
                      int* __restrict__ bins) {
  __shared__ int cur[NB];
  int tid = threadIdx.x, blk = blockIdx.x;
  for (int b = tid; b < NB; b += 256) cur[b] = offs[b * NBB + blk];
  __syncthreads();
  const int2* s2 = (const int2*)(ei + blk * CHUNK);
  const int2* d2 = (const int2*)(ei + N_EDGES + blk * CHUNK);
  for (int i = tid; i < CHUNK / 2; i += 256) {
    int2 s = s2[i];
    int2 d = d2[i];
    int p0 = atomicAdd(&cur[d.x >> 6], 1);
    bins[p0] = s.x | ((d.x & 63) << 16);
    int p1 = atomicAdd(&cur[d.y >> 6], 1);
    bins[p1] = s.y | ((d.y & 63) << 16);
  }
}

// ---------------- per-bucket sort -> padded per-node CSR + dinv + xp ------
__global__ __launch_bounds__(256, 4) void k_sort(
    const int* __restrict__ bins, const int* __restrict__ boff,
    const float* __restrict__ x,
    ushort_t* __restrict__ srcp, int2* __restrict__ rowiv,
    float* __restrict__ dinv, _Float16* __restrict__ xp) {
  __shared__ int dg[64], lo[64], cur[64];
  __shared__ float sdin[64];
  __shared__ int Tsh;
  __shared__ ushort_t buf[8192];
  int tid = threadIdx.x, b = blockIdx.x;
  int start = boff[b], end = boff[b + 1];
  if (tid < 64) dg[tid] = 0;
  __syncthreads();
  for (int i = start + tid; i < end; i += 256)
    atomicAdd(&dg[bins[i] >> 16], 1);
  __syncthreads();
  int pdv = 0;
  if (tid < 64) { pdv = (dg[tid] + 7) & ~7; lo[tid] = pdv; }
  __syncthreads();
  for (int off = 1; off < 64; off <<= 1) {
    int u = 0;
    if (tid < 64 && tid >= off) u = lo[tid - off];
    __syncthreads();
    if (tid < 64) lo[tid] += u;
    __syncthreads();
  }
  int ex = 0;
  if (tid < 64) {
    ex = lo[tid] - pdv;       // exclusive padded offset
    cur[tid] = ex;
    if (tid == 63) Tsh = lo[63];
  }
  __syncthreads();
  int T = Tsh;
  int base = start + b * 512;  // 512 >= 64*7 max padding slack per bucket
  for (int i = tid; i < T; i += 256) buf[i] = (ushort_t)ZROW;
  __syncthreads();
  for (int i = start + tid; i < end; i += 256) {
    int v = bins[i];
    int dl = v >> 16;
    int p = atomicAdd(&cur[dl], 1);
    buf[p] = (ushort_t)(v & 0xFFFF);
  }
  __syncthreads();
  for (int i = tid; i < T; i += 256) srcp[base + i] = buf[i];
  if (tid < 64) {
    int v = b * 64 + tid;
    if (v < N_NODES) {
      rowiv[v] = make_int2(base + ex, pdv);
      float dv = rsqrtf((float)dg[tid] + 2.0f);
      dinv[v] = dv;
      sdin[tid] = dv;
    } else {
      sdin[tid] = 0.f;
    }
  }
  __syncthreads();
  int nb64 = b * 4096;  // b*64*64
  for (int idx = tid; idx < 4096; idx += 256) {
    int v = b * 64 + (idx >> 6);
    if (v < N_NODES) xp[nb64 + idx] = (_Float16)(sdin[idx >> 6] * x[nb64 + idx]);
  }
  if (b == 0 && tid < 64) xp[ZROW * 64 + tid] = (_Float16)0.f;
}

// ========== weight prep: compose + pack B-fragments in one kernel ==========
// (verified correct in round 6) Bzh[t]: lane=(t>>3)&63, j=t&7; ntile=t>>10,
// ks=(t>>9)&1; n=ntile*16+(lane&15), k=ks*32+((lane>>4)<<3)+j.
__global__ __launch_bounds__(256) void k_wprep(
    const float* __restrict__ Wz, const float* __restrict__ bz,
    const float* __restrict__ Wlz, const float* __restrict__ blz,
    const float* __restrict__ Wh, const float* __restrict__ bh,
    const float* __restrict__ Wlh, const float* __restrict__ blh,
    const float* __restrict__ Wout,
    float2* __restrict__ B2, _Float16* __restrict__ Bzh,
    _Float16* __restrict__ Bwo) {
  int t = blockIdx.x * 256 + threadIdx.x;   // 8192 threads
  {
    int lane = (t >> 3) & 63, j = t & 7;
    int ntile = t >> 10, ks = (t >> 9) & 1;
    int n = ntile * 16 + (lane & 15);
    int k = ks * 32 + ((lane >> 4) << 3) + j;
    float acc = 0.f;
    if (n < 64) {
      for (int q = 0; q < 64; ++q) acc = fmaf(Wz[k * 64 + q], Wlz[q * 64 + n], acc);
    } else {
      int n2 = n - 64;
      for (int q = 0; q < 64; ++q) acc = fmaf(Wh[k * 64 + q], Wlh[q * 64 + n2], acc);
    }
    Bzh[t] = (_Float16)acc;
  }
  if (t < 3072) {
    int lane = (t >> 3) & 63, j = t & 7;
    int ntile = t >> 10, ks = (t >> 9) & 1;
    int n = ntile * 16 + (lane & 15);
    int k = ks * 32 + ((lane >> 4) << 3) + j;
    Bwo[t] = (_Float16)((n < 45) ? Wout[k * 45 + n] : 0.f);
  }
  if (t < 64) {
    float vz = blz[t], vh = blh[t];
    for (int q = 0; q < 64; ++q) {
      vz = fmaf(bz[q], Wlz[q * 64 + t], vz);
      vh = fmaf(bh[q], Wlh[q * 64 + t], vh);
    }
    B2[t] = make_float2(vz, vh);
  }
}

// ---------------- gather: 4 edges per wave-load ----------------
// lane = grp(edge slot, lane>>4) x sub(channel quad, lane&15).
// Each step: ds_bpermute distributes 4 srcs; each lane loads 8B (half4) of
// its slot's row -> one dwordx2 load covers 4 edges. fp32 accumulate.
// Cross-slot reduce: shfl_xor 16/32. sx written fp16 by lanes 0..15.
__global__ __launch_bounds__(256) void k_agg(
    const ushort_t* __restrict__ srcp, const int2* __restrict__ rowiv,
    const float* __restrict__ dinv, const _Float16* __restrict__ xp,
    _Float16* __restrict__ sxg) {
  int tid = threadIdx.x;
  int lane = tid & 63;
  int grp = lane >> 4;          // edge slot 0..3
  int sub = lane & 15;          // channels sub*4 .. sub*4+3
  int chOff = sub << 2;
  int w = blockIdx.x * 4 + (tid >> 6);
  int nw = gridDim.x * 4;
  for (int v = w; v < N_NODES; v += nw) {
    int vu = __builtin_amdgcn_readfirstlane(v);
    int2 ri = rowiv[vu];
    int beg = ri.x, pd = ri.y;    // pd multiple of 8
    float aA0 = 0.f, aA1 = 0.f, aA2 = 0.f, aA3 = 0.f;
    float aB0 = 0.f, aB1 = 0.f, aB2 = 0.f, aB3 = 0.f;
    for (int e = beg; e < beg + pd; e += 64) {
      int rem = beg + pd - e;
      int m = rem < 64 ? rem : 64;   // multiple of 8
      int sv = (lane < m) ? (int)srcp[e + lane] : ZROW;
      for (int t = 0; t < m; t += 8) {
        int sA = __builtin_amdgcn_ds_bpermute((t + grp) << 2, sv);
        int sB = __builtin_amdgcn_ds_bpermute((t + 4 + grp) << 2, sv);
        v4h rA = *(const v4h*)(xp + (sA << 6) + chOff);
        v4h rB = *(const v4h*)(xp + (sB << 6) + chOff);
        aA0 += (float)rA[0]; aA1 += (float)rA[1];
        aA2 += (float)rA[2]; aA3 += (float)rA[3];
        aB0 += (float)rB[0]; aB1 += (float)rB[1];
        aB2 += (float)rB[2]; aB3 += (float)rB[3];
      }
    }
    float a0 = aA0 + aB0, a1 = aA1 + aB1, a2 = aA2 + aB2, a3 = aA3 + aB3;
    a0 += __shfl_xor(a0, 16); a1 += __shfl_xor(a1, 16);
    a2 += __shfl_xor(a2, 16); a3 += __shfl_xor(a3, 16);
    a0 += __shfl_xor(a0, 32); a1 += __shfl_xor(a1, 32);
    a2 += __shfl_xor(a2, 32); a3 += __shfl_xor(a3, 32);
    if (lane < 16) {
      float dv = dinv[vu];
      v4h self = *(const v4h*)(xp + (vu << 6) + chOff);
      v4h o;
      o[0] = (_Float16)(dv * a0 + 2.f * dv * (float)self[0]);
      o[1] = (_Float16)(dv * a1 + 2.f * dv * (float)self[1]);
      o[2] = (_Float16)(dv * a2 + 2.f * dv * (float)self[2]);
      o[3] = (_Float16)(dv * a3 + 2.f * dv * (float)self[3]);
      *(v4h*)(sxg + (vu << 6) + chOff) = o;
    }
  }
}

// ---------------- MFMA cell + readout (one wave per 16-node tile) ---------
__global__ __launch_bounds__(256) void k_cell(
    const _Float16* __restrict__ sxg, const _Float16* __restrict__ Bzh,
    const _Float16* __restrict__ Bwo, const float2* __restrict__ B2,
    const float* __restrict__ bout, float* __restrict__ out) {
  __shared__ __align__(16) _Float16 tbuf[4][16][72];
  int tid = threadIdx.x;
  int lane = tid & 63, wv = tid >> 6;
  int l15 = lane & 15, quad = lane >> 4;
  int tile = blockIdx.x * 4 + wv;
  if (tile >= NTILES) return;    // no barriers in this kernel -> safe

  v8h bzf[8][2], bwf[3][2];
  #pragma unroll
  for (int t = 0; t < 8; ++t)
    #pragma unroll
    for (int ks = 0; ks < 2; ++ks)
      bzf[t][ks] = *(const v8h*)(Bzh + (((t * 2 + ks) * 64 + lane) << 3));
  #pragma unroll
  for (int t = 0; t < 3; ++t)
    #pragma unroll
    for (int ks = 0; ks < 2; ++ks)
      bwf[t][ks] = *(const v8h*)(Bwo + (((t * 2 + ks) * 64 + lane) << 3));
  float zb[4], hb[4], ob[3];
  #pragma unroll
  for (int t = 0; t < 4; ++t) {
    float2 bb = B2[t * 16 + l15];
    zb[t] = bb.x; hb[t] = bb.y;
  }
  #pragma unroll
  for (int t = 0; t < 3; ++t) {
    int c = t * 16 + l15;
    ob[t] = (c < 45) ? bout[c] : 0.f;
  }

  const _Float16* ar = sxg + (tile * 16 + l15) * 64 + quad * 8;
  v8h a0 = *(const v8h*)ar;
  v8h a1 = *(const v8h*)(ar + 32);

  f32x4_t accz[8];
  #pragma unroll
  for (int t = 0; t < 8; ++t) {
    f32x4_t c4 = {0.f, 0.f, 0.f, 0.f};
    c4 = __builtin_amdgcn_mfma_f32_16x16x32_f16(a0, bzf[t][0], c4, 0, 0, 0);
    c4 = __builtin_amdgcn_mfma_f32_16x16x32_f16(a1, bzf[t][1], c4, 0, 0, 0);
    accz[t] = c4;
  }

  #pragma unroll
  for (int t = 0; t < 4; ++t) {
    #pragma unroll
    for (int r = 0; r < 4; ++r) {
      float zv = accz[t][r] + zb[t];
      float hv = accz[t + 4][r] + hb[t];
      float Z = 1.f / (1.f + __expf(-zv));
      float tt = fminf(15.f, fmaxf(-15.f, hv));
      float e2 = __expf(-2.f * tt);
      float Th = (1.f - e2) / (1.f + e2);
      tbuf[wv][quad * 4 + r][t * 16 + l15] = (_Float16)fmaxf((1.f - Z) * Th, 0.f);
    }
  }
  __asm__ volatile("s_waitcnt lgkmcnt(0)" ::: "memory");

  v8h p0 = *(const v8h*)&tbuf[wv][l15][quad * 8];
  v8h p1 = *(const v8h*)&tbuf[wv][l15][32 + quad * 8];

  #pragma unroll
  for (int t = 0; t < 3; ++t) {
    f32x4_t o4 = {0.f, 0.f, 0.f, 0.f};
    o4 = __builtin_amdgcn_mfma_f32_16x16x32_f16(p0, bwf[t][0], o4, 0, 0, 0);
    o4 = __builtin_amdgcn_mfma_f32_16x16x32_f16(p1, bwf[t][1], o4, 0, 0, 0);
    int c = t * 16 + l15;
    if (c < 45) {
      #pragma unroll
      for (int r = 0; r < 4; ++r)
        out[(tile * 16 + quad * 4 + r) * 45 + c] = o4[r] + ob[t];
    }
  }
}

// ---------------- launch ----------------
extern "C" void kernel_launch(void* const* d_in, const int* in_sizes, int n_in,
                              void* d_out, int out_size, void* d_ws, size_t ws_size,
                              hipStream_t stream) {
  const float* x    = (const float*)d_in[0];
  const int*   ei   = (const int*)d_in[1];
  const float* Wz   = (const float*)d_in[2];
  const float* bz   = (const float*)d_in[3];
  const float* Wlz  = (const float*)d_in[4];
  const float* blz  = (const float*)d_in[5];
  // d_in[6..9] (W_r branch) dead: H=0 => H*R=0.
  const float* Wh   = (const float*)d_in[10];
  const float* bh   = (const float*)d_in[11];
  const float* Wlh  = (const float*)d_in[12];
  const float* blh  = (const float*)d_in[13];
  const float* Wout = (const float*)d_in[14];
  const float* bout = (const float*)d_in[15];
  float* out = (float*)d_out;

  char* w = (char*)d_ws;
  int*      cnt   = (int*)(w + 0);            // 0.8 MB
  int*      bins  = (int*)(w + 800768);       // 6.4 MB
  _Float16* sxg   = (_Float16*)(w + 0);       // 6.4 MB (aliases cnt+bins)
  ushort_t* srcp  = (ushort_t*)(w + 12800000);// ~4.0 MB
  int2*     rowiv = (int2*)(w + 16801024);    // 0.4 MB
  float*    dinv  = (float*)(w + 17201024);   // 0.2 MB
  int*      bsum  = (int*)(w + 17401024);     // 782 ints
  int*      boff  = (int*)(w + 17404160);     // 783 ints
  float2*   B2    = (float2*)(w + 17440128);  // 512 B
  _Float16* Bzh   = (_Float16*)(w + 17440768);// 16 KB
  _Float16* Bwo   = (_Float16*)(w + 17457152);// 6 KB
  _Float16* xp    = (_Float16*)(w + 17463296);// 6.4 MB
  // total ~23.9 MB

  k_wprep<<<32, 256, 0, stream>>>(Wz, bz, Wlz, blz, Wh, bh, Wlh, blh, Wout,
                                  B2, Bzh, Bwo);
  k_hist <<<NBB, 256, 0, stream>>>(ei, cnt);
  k_scanA<<<NB, 256, 0, stream>>>(cnt, bsum);
  k_scanB<<<1, 1024, 0, stream>>>(bsum, boff);
  k_scanC<<<NB, 256, 0, stream>>>(cnt, boff);
  k_bin  <<<NBB, 256, 0, stream>>>(ei, cnt, bins);
  k_sort <<<NB, 256, 0, stream>>>(bins, boff, x, srcp, rowiv, dinv, xp);
  k_agg  <<<2048, 256, 0, stream>>>(srcp, rowiv, dinv, xp, sxg);
  k_cell <<<NB, 256, 0, stream>>>(sxg, Bzh, Bwo, B2, bout, out);
}

// Round 8
// 166.269 us; speedup vs baseline: 2.1803x; 1.0768x over previous
//
#include <hip/hip_runtime.h>

#define N_NODES 50000
#define N_EDGES 1600000
#define NB 782            // buckets of 64 dst nodes: ceil(50000/64)
#define NBB 256           // binning blocks
#define CHUNK 6250        // N_EDGES / NBB (exact, even)
#define CAP 2560          // fixed bucket capacity (max ~2200 = 2046 + 11 sigma)
#define SCAP 3072         // srcp per-bucket capacity (CAP + 512 pad slack)
#define ZROW 50000        // dummy src row (all zeros) for padding
#define NTILES 3125       // 50000 / 16 exact

typedef unsigned short ushort_t;
typedef _Float16 v8h __attribute__((ext_vector_type(8)));
typedef _Float16 v4h __attribute__((ext_vector_type(4)));
typedef float f32x4_t __attribute__((ext_vector_type(4)));

// ========== weight prep: compose + pack B-fragments + zero gcur ==========
// Bzh[t]: lane=(t>>3)&63, j=t&7; ntile=t>>10, ks=(t>>9)&1;
// n=ntile*16+(lane&15), k=ks*32+((lane>>4)<<3)+j. (verified round 6/7)
__global__ __launch_bounds__(256) void k_wprep(
    const float* __restrict__ Wz, const float* __restrict__ bz,
    const float* __restrict__ Wlz, const float* __restrict__ blz,
    const float* __restrict__ Wh, const float* __restrict__ bh,
    const float* __restrict__ Wlh, const float* __restrict__ blh,
    const float* __restrict__ Wout,
    float2* __restrict__ B2, _Float16* __restrict__ Bzh,
    _Float16* __restrict__ Bwo, int* __restrict__ gcur) {
  int t = blockIdx.x * 256 + threadIdx.x;   // 8192 threads
  {
    int lane = (t >> 3) & 63, j = t & 7;
    int ntile = t >> 10, ks = (t >> 9) & 1;
    int n = ntile * 16 + (lane & 15);
    int k = ks * 32 + ((lane >> 4) << 3) + j;
    float acc = 0.f;
    if (n < 64) {
      for (int q = 0; q < 64; ++q) acc = fmaf(Wz[k * 64 + q], Wlz[q * 64 + n], acc);
    } else {
      int n2 = n - 64;
      for (int q = 0; q < 64; ++q) acc = fmaf(Wh[k * 64 + q], Wlh[q * 64 + n2], acc);
    }
    Bzh[t] = (_Float16)acc;
  }
  if (t < 3072) {
    int lane = (t >> 3) & 63, j = t & 7;
    int ntile = t >> 10, ks = (t >> 9) & 1;
    int n = ntile * 16 + (lane & 15);
    int k = ks * 32 + ((lane >> 4) << 3) + j;
    Bwo[t] = (_Float16)((n < 45) ? Wout[k * 45 + n] : 0.f);
  }
  if (t < 64) {
    float vz = blz[t], vh = blh[t];
    for (int q = 0; q < 64; ++q) {
      vz = fmaf(bz[q], Wlz[q * 64 + t], vz);
      vh = fmaf(bh[q], Wlh[q * 64 + t], vh);
    }
    B2[t] = make_float2(vz, vh);
  }
  if (t < NB) gcur[t] = 0;
}

// ========== fused binning: one pass over edges, fixed-CAP buckets ==========
// (a) read src+dst once, pack (src | dl<<16 | bucket<<22) into LDS + LDS hist
// (b) reserve per-bucket segment via one global atomicAdd per (block,bucket)
// (c) scatter from LDS into bins[b*CAP + seg + pos]
__global__ __launch_bounds__(256) void k_bin2(
    const int* __restrict__ ei, int* __restrict__ gcur, int* __restrict__ bins) {
  __shared__ int h[NB];
  __shared__ int segb[NB];
  __shared__ int pk[CHUNK];     // 25 KB
  int tid = threadIdx.x, blk = blockIdx.x;
  for (int i = tid; i < NB; i += 256) h[i] = 0;
  __syncthreads();
  const int2* s2 = (const int2*)(ei + blk * CHUNK);
  const int2* d2 = (const int2*)(ei + N_EDGES + blk * CHUNK);
  for (int i = tid; i < CHUNK / 2; i += 256) {
    int2 s = s2[i];
    int2 d = d2[i];
    pk[2 * i]     = s.x | ((d.x & 63) << 16) | ((d.x >> 6) << 22);
    pk[2 * i + 1] = s.y | ((d.y & 63) << 16) | ((d.y >> 6) << 22);
    atomicAdd(&h[d.x >> 6], 1);
    atomicAdd(&h[d.y >> 6], 1);
  }
  __syncthreads();
  for (int b = tid; b < NB; b += 256) {
    int c = h[b];
    segb[b] = c ? atomicAdd(&gcur[b], c) : 0;
    h[b] = 0;                       // reuse as local cursor
  }
  __syncthreads();
  for (int i = tid; i < CHUNK; i += 256) {
    int v = pk[i];
    int b = (unsigned)v >> 22;
    int p = atomicAdd(&h[b], 1);
    bins[b * CAP + segb[b] + p] = v & 0x3FFFFF;   // src | dl<<16
  }
}

// ---------------- per-bucket sort -> padded per-node CSR + dinv + xp ------
__global__ __launch_bounds__(256, 4) void k_sort(
    const int* __restrict__ bins, const int* __restrict__ gcur,
    const float* __restrict__ x,
    ushort_t* __restrict__ srcp, int2* __restrict__ rowiv,
    float* __restrict__ dinv, _Float16* __restrict__ xp) {
  __shared__ int dg[64], lo[64], cur[64];
  __shared__ float sdin[64];
  __shared__ int Tsh;
  __shared__ ushort_t buf[8192];
  int tid = threadIdx.x, b = blockIdx.x;
  int start = b * CAP, end = start + gcur[b];
  if (tid < 64) dg[tid] = 0;
  __syncthreads();
  for (int i = start + tid; i < end; i += 256)
    atomicAdd(&dg[bins[i] >> 16], 1);
  __syncthreads();
  int pdv = 0;
  if (tid < 64) { pdv = (dg[tid] + 7) & ~7; lo[tid] = pdv; }
  __syncthreads();
  for (int off = 1; off < 64; off <<= 1) {
    int u = 0;
    if (tid < 64 && tid >= off) u = lo[tid - off];
    __syncthreads();
    if (tid < 64) lo[tid] += u;
    __syncthreads();
  }
  int ex = 0;
  if (tid < 64) {
    ex = lo[tid] - pdv;       // exclusive padded offset
    cur[tid] = ex;
    if (tid == 63) Tsh = lo[63];
  }
  __syncthreads();
  int T = Tsh;
  int base = b * SCAP;        // fixed per-bucket srcp region
  for (int i = tid; i < T; i += 256) buf[i] = (ushort_t)ZROW;
  __syncthreads();
  for (int i = start + tid; i < end; i += 256) {
    int v = bins[i];
    int dl = v >> 16;
    int p = atomicAdd(&cur[dl], 1);
    buf[p] = (ushort_t)(v & 0xFFFF);
  }
  __syncthreads();
  for (int i = tid; i < T; i += 256) srcp[base + i] = buf[i];
  if (tid < 64) {
    int v = b * 64 + tid;
    if (v < N_NODES) {
      rowiv[v] = make_int2(base + ex, pdv);
      float dv = rsqrtf((float)dg[tid] + 2.0f);
      dinv[v] = dv;
      sdin[tid] = dv;
    } else {
      sdin[tid] = 0.f;
    }
  }
  __syncthreads();
  int nb64 = b * 4096;  // b*64*64
  for (int idx = tid; idx < 4096; idx += 256) {
    int v = b * 64 + (idx >> 6);
    if (v < N_NODES) xp[nb64 + idx] = (_Float16)(sdin[idx >> 6] * x[nb64 + idx]);
  }
  if (b == 0 && tid < 64) xp[ZROW * 64 + tid] = (_Float16)0.f;
}

// ---------------- gather: 4 edges per wave-load ----------------
// lane = grp(edge slot, lane>>4) x sub(channel quad, lane&15).
__global__ __launch_bounds__(256) void k_agg(
    const ushort_t* __restrict__ srcp, const int2* __restrict__ rowiv,
    const float* __restrict__ dinv, const _Float16* __restrict__ xp,
    _Float16* __restrict__ sxg) {
  int tid = threadIdx.x;
  int lane = tid & 63;
  int grp = lane >> 4;          // edge slot 0..3
  int sub = lane & 15;          // channels sub*4 .. sub*4+3
  int chOff = sub << 2;
  int w = blockIdx.x * 4 + (tid >> 6);
  int nw = gridDim.x * 4;
  for (int v = w; v < N_NODES; v += nw) {
    int vu = __builtin_amdgcn_readfirstlane(v);
    int2 ri = rowiv[vu];
    int beg = ri.x, pd = ri.y;    // pd multiple of 8
    float aA0 = 0.f, aA1 = 0.f, aA2 = 0.f, aA3 = 0.f;
    float aB0 = 0.f, aB1 = 0.f, aB2 = 0.f, aB3 = 0.f;
    for (int e = beg; e < beg + pd; e += 64) {
      int rem = beg + pd - e;
      int m = rem < 64 ? rem : 64;   // multiple of 8
      int sv = (lane < m) ? (int)srcp[e + lane] : ZROW;
      for (int t = 0; t < m; t += 8) {
        int sA = __builtin_amdgcn_ds_bpermute((t + grp) << 2, sv);
        int sB = __builtin_amdgcn_ds_bpermute((t + 4 + grp) << 2, sv);
        v4h rA = *(const v4h*)(xp + (sA << 6) + chOff);
        v4h rB = *(const v4h*)(xp + (sB << 6) + chOff);
        aA0 += (float)rA[0]; aA1 += (float)rA[1];
        aA2 += (float)rA[2]; aA3 += (float)rA[3];
        aB0 += (float)rB[0]; aB1 += (float)rB[1];
        aB2 += (float)rB[2]; aB3 += (float)rB[3];
      }
    }
    float a0 = aA0 + aB0, a1 = aA1 + aB1, a2 = aA2 + aB2, a3 = aA3 + aB3;
    a0 += __shfl_xor(a0, 16); a1 += __shfl_xor(a1, 16);
    a2 += __shfl_xor(a2, 16); a3 += __shfl_xor(a3, 16);
    a0 += __shfl_xor(a0, 32); a1 += __shfl_xor(a1, 32);
    a2 += __shfl_xor(a2, 32); a3 += __shfl_xor(a3, 32);
    if (lane < 16) {
      float dv = dinv[vu];
      v4h self = *(const v4h*)(xp + (vu << 6) + chOff);
      v4h o;
      o[0] = (_Float16)(dv * a0 + 2.f * dv * (float)self[0]);
      o[1] = (_Float16)(dv * a1 + 2.f * dv * (float)self[1]);
      o[2] = (_Float16)(dv * a2 + 2.f * dv * (float)self[2]);
      o[3] = (_Float16)(dv * a3 + 2.f * dv * (float)self[3]);
      *(v4h*)(sxg + (vu << 6) + chOff) = o;
    }
  }
}

// ---------------- MFMA cell + readout (one wave per 16-node tile) ---------
__global__ __launch_bounds__(256) void k_cell(
    const _Float16* __restrict__ sxg, const _Float16* __restrict__ Bzh,
    const _Float16* __restrict__ Bwo, const float2* __restrict__ B2,
    const float* __restrict__ bout, float* __restrict__ out) {
  __shared__ __align__(16) _Float16 tbuf[4][16][72];
  int tid = threadIdx.x;
  int lane = tid & 63, wv = tid >> 6;
  int l15 = lane & 15, quad = lane >> 4;
  int tile = blockIdx.x * 4 + wv;
  if (tile >= NTILES) return;    // no barriers in this kernel -> safe

  v8h bzf[8][2], bwf[3][2];
  #pragma unroll
  for (int t = 0; t < 8; ++t)
    #pragma unroll
    for (int ks = 0; ks < 2; ++ks)
      bzf[t][ks] = *(const v8h*)(Bzh + (((t * 2 + ks) * 64 + lane) << 3));
  #pragma unroll
  for (int t = 0; t < 3; ++t)
    #pragma unroll
    for (int ks = 0; ks < 2; ++ks)
      bwf[t][ks] = *(const v8h*)(Bwo + (((t * 2 + ks) * 64 + lane) << 3));
  float zb[4], hb[4], ob[3];
  #pragma unroll
  for (int t = 0; t < 4; ++t) {
    float2 bb = B2[t * 16 + l15];
    zb[t] = bb.x; hb[t] = bb.y;
  }
  #pragma unroll
  for (int t = 0; t < 3; ++t) {
    int c = t * 16 + l15;
    ob[t] = (c < 45) ? bout[c] : 0.f;
  }

  const _Float16* ar = sxg + (tile * 16 + l15) * 64 + quad * 8;
  v8h a0 = *(const v8h*)ar;
  v8h a1 = *(const v8h*)(ar + 32);

  f32x4_t accz[8];
  #pragma unroll
  for (int t = 0; t < 8; ++t) {
    f32x4_t c4 = {0.f, 0.f, 0.f, 0.f};
    c4 = __builtin_amdgcn_mfma_f32_16x16x32_f16(a0, bzf[t][0], c4, 0, 0, 0);
    c4 = __builtin_amdgcn_mfma_f32_16x16x32_f16(a1, bzf[t][1], c4, 0, 0, 0);
    accz[t] = c4;
  }

  #pragma unroll
  for (int t = 0; t < 4; ++t) {
    #pragma unroll
    for (int r = 0; r < 4; ++r) {
      float zv = accz[t][r] + zb[t];
      float hv = accz[t + 4][r] + hb[t];
      float Z = 1.f / (1.f + __expf(-zv));
      float tt = fminf(15.f, fmaxf(-15.f, hv));
      float e2 = __expf(-2.f * tt);
      float Th = (1.f - e2) / (1.f + e2);
      tbuf[wv][quad * 4 + r][t * 16 + l15] = (_Float16)fmaxf((1.f - Z) * Th, 0.f);
    }
  }
  __asm__ volatile("s_waitcnt lgkmcnt(0)" ::: "memory");

  v8h p0 = *(const v8h*)&tbuf[wv][l15][quad * 8];
  v8h p1 = *(const v8h*)&tbuf[wv][l15][32 + quad * 8];

  #pragma unroll
  for (int t = 0; t < 3; ++t) {
    f32x4_t o4 = {0.f, 0.f, 0.f, 0.f};
    o4 = __builtin_amdgcn_mfma_f32_16x16x32_f16(p0, bwf[t][0], o4, 0, 0, 0);
    o4 = __builtin_amdgcn_mfma_f32_16x16x32_f16(p1, bwf[t][1], o4, 0, 0, 0);
    int c = t * 16 + l15;
    if (c < 45) {
      #pragma unroll
      for (int r = 0; r < 4; ++r)
        out[(tile * 16 + quad * 4 + r) * 45 + c] = o4[r] + ob[t];
    }
  }
}

// ---------------- launch ----------------
extern "C" void kernel_launch(void* const* d_in, const int* in_sizes, int n_in,
                              void* d_out, int out_size, void* d_ws, size_t ws_size,
                              hipStream_t stream) {
  const float* x    = (const float*)d_in[0];
  const int*   ei   = (const int*)d_in[1];
  const float* Wz   = (const float*)d_in[2];
  const float* bz   = (const float*)d_in[3];
  const float* Wlz  = (const float*)d_in[4];
  const float* blz  = (const float*)d_in[5];
  // d_in[6..9] (W_r branch) dead: H=0 => H*R=0.
  const float* Wh   = (const float*)d_in[10];
  const float* bh   = (const float*)d_in[11];
  const float* Wlh  = (const float*)d_in[12];
  const float* blh  = (const float*)d_in[13];
  const float* Wout = (const float*)d_in[14];
  const float* bout = (const float*)d_in[15];
  float* out = (float*)d_out;

  char* w = (char*)d_ws;
  // bins (early) and sxg (late) alias: bins dead after k_sort, sxg written
  // by k_agg afterwards.
  int*      bins  = (int*)(w + 0);            // 782*2560*4 = 8,007,680
  _Float16* sxg   = (_Float16*)(w + 0);       // 6,400,000 (alias)
  int*      gcur  = (int*)(w + 8007680);      // 3,128
  ushort_t* srcp  = (ushort_t*)(w + 8010816); // 782*3072*2 = 4,804,608
  int2*     rowiv = (int2*)(w + 12815424);    // 400,000
  float*    dinv  = (float*)(w + 13215424);   // 200,000
  float2*   B2    = (float2*)(w + 13415424);  // 512
  _Float16* Bzh   = (_Float16*)(w + 13415936);// 16,384
  _Float16* Bwo   = (_Float16*)(w + 13432320);// 6,144
  _Float16* xp    = (_Float16*)(w + 13438464);// 6,400,128 -> ends ~19.8 MB

  k_wprep<<<32, 256, 0, stream>>>(Wz, bz, Wlz, blz, Wh, bh, Wlh, blh, Wout,
                                  B2, Bzh, Bwo, gcur);
  k_bin2 <<<NBB, 256, 0, stream>>>(ei, gcur, bins);
  k_sort <<<NB, 256, 0, stream>>>(bins, gcur, x, srcp, rowiv, dinv, xp);
  k_agg  <<<2048, 256, 0, stream>>>(srcp, rowiv, dinv, xp, sxg);
  k_cell <<<NB, 256, 0, stream>>>(sxg, Bzh, Bwo, B2, bout, out);
}